// Round 5
// baseline (660.758 us; speedup 1.0000x reference)
//
#include <hip/hip_runtime.h>
#include <math.h>

// ---------------------------------------------------------------------------
// FFT_MLP_KAN: FFT features -> 4 fused KAN layers (dense 14-feature GEMM with
// vectorized LDS) -> 3 folded MLP heads. All fp32 (sign-flip safety: final
// sigmoid inputs are ~1e6 scale; bf16 paths risk category flips).
// B = 8192, dims 504->80->160->80->40 -> 3.
// ---------------------------------------------------------------------------

__device__ __forceinline__ float silu_f(float x) {
    return x / (1.f + __expf(-x));
}

// ---------------------------------------------------------------------------
// FFT feature kernel (unchanged from passing round-1 kernel).
// ---------------------------------------------------------------------------
__global__ __launch_bounds__(128) void fft_kernel(const float* __restrict__ x,
                                                  float* __restrict__ F0, int P) {
    __shared__ float xs[128 * 65];
    __shared__ float twc[288], tws[288];    // cos / sin(-2*pi*k*n/32)
    int tid = threadIdx.x;
    for (int t = tid; t < 288; t += 128) {
        int k = t >> 5, n = t & 31;
        int m = (k * n) & 31;
        float ang = -0.19634954084936207f * (float)m;
        float s, c;
        sincosf(ang, &s, &c);
        twc[t] = c; tws[t] = s;
    }
    int p0 = blockIdx.x * 128;
    for (int idx = tid; idx < 128 * 64; idx += 128) {
        int g = p0 * 64 + idx;
        float v = (g < P * 64) ? x[g] : 0.f;
        xs[(idx >> 6) * 65 + (idx & 63)] = v;
    }
    __syncthreads();
    int p = p0 + tid;
    if (p >= P) return;
    const float* row = &xs[tid * 65];
    float r[64];
#pragma unroll
    for (int n = 0; n < 64; ++n) r[n] = row[n];
    float outv[36];
#pragma unroll
    for (int k = 0; k < 9; ++k) {
        float rp = 0.f, ip = 0.f, rc = 0.f, ic = 0.f;
#pragma unroll
        for (int n = 0; n < 32; ++n) {
            float c = twc[k * 32 + n], s = tws[k * 32 + n];
            rp = fmaf(r[n], c, rp);
            ip = fmaf(r[n], s, ip);
            rc = fmaf(r[n + 32], c, rc);
            ic = fmaf(r[n + 32], s, ic);
        }
        float ap = sqrtf(fmaf(rp, rp, ip * ip));
        float ac = sqrtf(fmaf(rc, rc, ic * ic));
        float gc = atan2f(ic, rc);
        outv[k] = ap; outv[9 + k] = gc; outv[18 + k] = ac; outv[27 + k] = gc;
    }
    float* dst = &F0[(size_t)p * 36];
#pragma unroll
    for (int q = 0; q < 36; ++q) dst[q] = outv[q];
}

// ---------------------------------------------------------------------------
// Fused-weight prep: Wf[(i*14 + c)*OUT + o]; c=0 -> base_w, c>=1 -> spline*scaler
// ---------------------------------------------------------------------------
__global__ void prep_kan_kernel(float* __restrict__ Wf, const float* __restrict__ base_w,
                                const float* __restrict__ spline_w,
                                const float* __restrict__ scaler, int IN, int OUT) {
    int id = blockIdx.x * 256 + threadIdx.x;
    int total = IN * 14 * OUT;
    if (id >= total) return;
    int o = id % OUT;
    int rem = id / OUT;
    int c = rem % 14;
    int i = rem / 14;
    float v;
    if (c == 0) v = base_w[o * IN + i];
    else        v = spline_w[((size_t)o * IN + i) * 13 + (c - 1)] * scaler[o * IN + i];
    Wf[id] = v;
}

// Heads fold: LeakyReLU(True) == identity, so y2 = h @ (W2@W1)^T + (W2@b1 + b2).
__global__ void prep_heads_kernel(float* __restrict__ W21, float* __restrict__ b21,
                                  const float* __restrict__ W1, const float* __restrict__ b1,
                                  const float* __restrict__ W2, const float* __restrict__ b2) {
    int id = blockIdx.x * 256 + threadIdx.x;
    if (id < 3 * 20 * 40) {
        int k = id % 40; int rem = id / 40; int j = rem % 20; int h = rem / 20;
        float a = 0.f;
        for (int m = 0; m < 40; ++m)
            a = fmaf(W2[(h * 20 + j) * 40 + m], W1[(h * 40 + m) * 40 + k], a);
        W21[id] = a;
    } else if (id < 3 * 20 * 40 + 60) {
        int t = id - 2400; int j = t % 20; int h = t / 20;
        float a = b2[h * 20 + j];
        for (int m = 0; m < 40; ++m)
            a = fmaf(W2[(h * 20 + j) * 40 + m], b1[h * 40 + m], a);
        b21[t] = a;
    }
}

// ---------------------------------------------------------------------------
// KAN layer v3: dense 14-feature GEMM, LDS fully vectorized.
//  - Ws LDS layout [k][c][ct][NRP=12]: 3x ds_read_b128 per (k,c) per thread.
//  - Ft LDS layout [k][c][row]: feature-transposed -> 2x b128 per (k,c).
//  - Thread t owns row t's float2 (chunk's 2 k-values), prefetched 1 ahead.
//  - 128 threads (2 waves), register tile MR x 10, split-K over blockIdx.y.
// ---------------------------------------------------------------------------
template <int OUT, int BM, int KC>
__global__ __launch_bounds__(128) void kan3_kernel(const float* __restrict__ X, int IN,
                                                   const float* __restrict__ Wf,
                                                   float* __restrict__ Yp, int B) {
    constexpr int NR = 10;
    constexpr int COLS_T = OUT / NR;
    constexpr int ROWS_T = 128 / COLS_T;
    constexpr int MR = BM / ROWS_T;
    constexpr int NRP = 12;
    static_assert(COLS_T * NR == OUT, "cols");
    static_assert(ROWS_T * MR == BM, "rows");
    static_assert(KC % 2 == 0, "even KC");
    static_assert(MR % 4 == 0, "vec rows");

    __shared__ float Ws[2 * 14 * COLS_T * NRP];
    __shared__ float Ft[2 * 14 * BM];

    int tid = threadIdx.x;
    int ct = tid % COLS_T, rt = tid / COLS_T;
    int b0 = blockIdx.x * BM;
    int ibase = blockIdx.y * KC;
    bool frow = (tid < BM);

    float acc[MR][NR];
#pragma unroll
    for (int m = 0; m < MR; ++m)
#pragma unroll
        for (int n = 0; n < NR; ++n) acc[m][n] = 0.f;

    // preload first chunk's x (row = tid, k = 0,1)
    float2 xv = make_float2(0.f, 0.f);
    if (frow) xv = *(const float2*)&X[(size_t)(b0 + tid) * IN + ibase];

    for (int i0 = 0; i0 < KC; i0 += 2) {
        // ---- feature build (thread owns one row, both k's) ----
        if (frow) {
#pragma unroll
            for (int k = 0; k < 2; ++k) {
                float xs = (k == 0) ? xv.x : xv.y;
                float* dst = &Ft[k * 14 * BM + tid];
                dst[0] = silu_f(xs);
#pragma unroll
                for (int c = 1; c < 14; ++c) dst[c * BM] = 0.f;
                float t10 = (xs + 0.3f) * 10.f;
                if (t10 >= 0.f && t10 < 16.f) {
                    int j = (int)t10;
                    float u = t10 - (float)j;
                    float u2 = u * u, u3 = u2 * u, v = 1.f - u;
                    float B0 = v * v * v * (1.f / 6.f);
                    float B1 = (3.f * u3 - 6.f * u2 + 4.f) * (1.f / 6.f);
                    float B2 = (-3.f * u3 + 3.f * u2 + 3.f * u + 1.f) * (1.f / 6.f);
                    float B3 = u3 * (1.f / 6.f);
                    int bs = j - 3;
#pragma unroll
                    for (int t = 0; t < 4; ++t) {
                        int rr = bs + t;
                        float bb = (t == 0) ? B0 : (t == 1) ? B1 : (t == 2) ? B2 : B3;
                        if (rr >= 0 && rr <= 12) dst[(1 + rr) * BM] = bb;
                    }
                }
            }
        }
        // ---- prefetch next chunk's x ----
        float2 xn = xv;
        if (frow && (i0 + 2) < KC)
            xn = *(const float2*)&X[(size_t)(b0 + tid) * IN + ibase + i0 + 2];
        // ---- stage weights (coalesced read, swizzled LDS write) ----
        {
            const float* wsrc = Wf + (size_t)(ibase + i0) * 14 * OUT;
            for (int t = tid; t < 2 * 14 * OUT; t += 128) {
                int o = t % OUT;
                int kc = t / OUT;
                Ws[(kc * COLS_T + o / NR) * NRP + (o % NR)] = wsrc[t];
            }
        }
        __syncthreads();
        // ---- FMA: 2 k's x 14 c, all-vector LDS reads ----
#pragma unroll
        for (int k = 0; k < 2; ++k) {
#pragma unroll
            for (int c = 0; c < 14; ++c) {
                const float* wb = &Ws[((k * 14 + c) * COLS_T + ct) * NRP];
                float4 w0 = *(const float4*)(wb);
                float4 w1 = *(const float4*)(wb + 4);
                float2 w2 = *(const float2*)(wb + 8);
                float wn[NR] = {w0.x, w0.y, w0.z, w0.w, w1.x, w1.y, w1.z, w1.w, w2.x, w2.y};
                const float* fb = &Ft[(k * 14 + c) * BM + rt * MR];
                float xm[MR];
#pragma unroll
                for (int mm = 0; mm < MR; mm += 4) {
                    float4 f = *(const float4*)(fb + mm);
                    xm[mm] = f.x; xm[mm + 1] = f.y; xm[mm + 2] = f.z; xm[mm + 3] = f.w;
                }
#pragma unroll
                for (int m = 0; m < MR; ++m)
#pragma unroll
                    for (int n = 0; n < NR; ++n) acc[m][n] = fmaf(xm[m], wn[n], acc[m][n]);
            }
        }
        __syncthreads();
        xv = xn;
    }

    // ---- store partial (float2 stores, 8B aligned) ----
    float* ybase = Yp + (size_t)blockIdx.y * B * OUT;
#pragma unroll
    for (int m = 0; m < MR; ++m) {
        float* yr = ybase + (size_t)(b0 + rt * MR + m) * OUT + ct * NR;
#pragma unroll
        for (int nn = 0; nn < NR / 2; ++nn)
            *(float2*)(yr + 2 * nn) = make_float2(acc[m][2 * nn], acc[m][2 * nn + 1]);
    }
}

__global__ void reduce_kernel(float* __restrict__ Y, const float* __restrict__ Yp,
                              int N, int KS) {
    int t = blockIdx.x * 256 + threadIdx.x;
    if (t >= N) return;
    float a = 0.f;
    for (int s = 0; s < KS; ++s) a += Yp[(size_t)s * N + t];
    Y[t] = a;
}

// ---------------------------------------------------------------------------
// Heads: one thread per (b, head).
// ---------------------------------------------------------------------------
__global__ __launch_bounds__(256) void heads_kernel(const float* __restrict__ h4,
                                                    const float* __restrict__ W21,
                                                    const float* __restrict__ b21,
                                                    const float* __restrict__ W3,
                                                    const float* __restrict__ b3,
                                                    float* __restrict__ out, int B) {
    __shared__ float w21s[2400], b21s[60], w3s[60], b3s[3];
    int tid = threadIdx.x;
    for (int t = tid; t < 2400; t += 256) w21s[t] = W21[t];
    if (tid < 60) { b21s[tid] = b21[tid]; w3s[tid] = W3[tid]; }
    if (tid < 3) b3s[tid] = b3[tid];
    __syncthreads();
    int id = blockIdx.x * 256 + tid;
    if (id >= B * 3) return;
    int b = id / 3, h = id % 3;
    const float* hr = &h4[(size_t)b * 40];
    float hv[40];
#pragma unroll
    for (int m = 0; m < 40; ++m) hv[m] = hr[m];
    float z = b3s[h];
#pragma unroll
    for (int j = 0; j < 20; ++j) {
        float y = b21s[h * 20 + j];
        const float* wr = &w21s[(h * 20 + j) * 40];
#pragma unroll
        for (int m = 0; m < 40; ++m) y = fmaf(wr[m], hv[m], y);
        y = (y >= 0.f) ? y : 0.05f * y;
        z = fmaf(w3s[h * 20 + j], y, z);
    }
    out[id] = 1.f / (1.f + __expf(-z));
}

// ---------------------------------------------------------------------------
extern "C" void kernel_launch(void* const* d_in, const int* in_sizes, int n_in,
                              void* d_out, int out_size, void* d_ws, size_t ws_size,
                              hipStream_t stream) {
    const float* x   = (const float*)d_in[0];
    const float* k1b = (const float*)d_in[1];
    const float* k1s = (const float*)d_in[2];
    const float* k1c = (const float*)d_in[3];
    const float* k2b = (const float*)d_in[4];
    const float* k2s = (const float*)d_in[5];
    const float* k2c = (const float*)d_in[6];
    const float* k3b = (const float*)d_in[7];
    const float* k3s = (const float*)d_in[8];
    const float* k3c = (const float*)d_in[9];
    const float* k4b = (const float*)d_in[10];
    const float* k4s = (const float*)d_in[11];
    const float* k4c = (const float*)d_in[12];
    const float* hW1 = (const float*)d_in[13];
    const float* hb1 = (const float*)d_in[14];
    const float* hW2 = (const float*)d_in[15];
    const float* hb2 = (const float*)d_in[16];
    const float* hW3 = (const float*)d_in[17];
    const float* hb3 = (const float*)d_in[18];
    float* out = (float*)d_out;

    int B = in_sizes[0] / (64 * 14);
    int P = B * 14;

    float* ws = (float*)d_ws;
    size_t off = 0;
    float* F0  = ws + off; off += (size_t)B * 504;
    float* h1  = ws + off; off += (size_t)B * 80;
    float* h2  = ws + off; off += (size_t)B * 160;
    float* h3  = ws + off; off += (size_t)B * 80;
    float* h4  = ws + off; off += (size_t)B * 40;
    float* Wf1 = ws + off; off += 504 * 14 * 80;
    float* Wf2 = ws + off; off += 80 * 14 * 160;
    float* Wf3 = ws + off; off += 160 * 14 * 80;
    float* Wf4 = ws + off; off += 80 * 14 * 40;
    float* W21 = ws + off; off += 2400;
    float* b21 = ws + off; off += 60;
    float* Yp  = ws + off; off += (size_t)B * 720;   // split-K partials (max 9x80)

    // ---- weight prep ----
    prep_kan_kernel<<<(504 * 14 * 80 + 255) / 256, 256, 0, stream>>>(Wf1, k1b, k1s, k1c, 504, 80);
    prep_kan_kernel<<<(80 * 14 * 160 + 255) / 256, 256, 0, stream>>>(Wf2, k2b, k2s, k2c, 80, 160);
    prep_kan_kernel<<<(160 * 14 * 80 + 255) / 256, 256, 0, stream>>>(Wf3, k3b, k3s, k3c, 160, 80);
    prep_kan_kernel<<<(80 * 14 * 40 + 255) / 256, 256, 0, stream>>>(Wf4, k4b, k4s, k4c, 80, 40);
    prep_heads_kernel<<<(2460 + 255) / 256, 256, 0, stream>>>(W21, b21, hW1, hb1, hW2, hb2);

    // ---- FFT features ----
    fft_kernel<<<(P + 127) / 128, 128, 0, stream>>>(x, F0, P);

    // ---- KAN layers (split-K + reduce) ----
    // L1: 504 -> 80, BM=128, S=9 (KC=56)
    kan3_kernel<80, 128, 56><<<dim3(B / 128, 9), 128, 0, stream>>>(F0, 504, Wf1, Yp, B);
    reduce_kernel<<<((B * 80) + 255) / 256, 256, 0, stream>>>(h1, Yp, B * 80, 9);
    // L2: 80 -> 160, BM=64, S=4 (KC=20)
    kan3_kernel<160, 64, 20><<<dim3(B / 64, 4), 128, 0, stream>>>(h1, 80, Wf2, Yp, B);
    reduce_kernel<<<((B * 160) + 255) / 256, 256, 0, stream>>>(h2, Yp, B * 160, 4);
    // L3: 160 -> 80, BM=128, S=8 (KC=20)
    kan3_kernel<80, 128, 20><<<dim3(B / 128, 8), 128, 0, stream>>>(h2, 160, Wf3, Yp, B);
    reduce_kernel<<<((B * 80) + 255) / 256, 256, 0, stream>>>(h3, Yp, B * 80, 8);
    // L4: 80 -> 40, BM=128, S=4 (KC=20)
    kan3_kernel<40, 128, 20><<<dim3(B / 128, 4), 128, 0, stream>>>(h3, 80, Wf4, Yp, B);
    reduce_kernel<<<((B * 40) + 255) / 256, 256, 0, stream>>>(h4, Yp, B * 40, 4);

    // ---- heads ----
    heads_kernel<<<(B * 3 + 255) / 256, 256, 0, stream>>>(h4, W21, b21, hW3, hb3, out, B);

    (void)n_in; (void)out_size; (void)ws_size;
}

// Round 6
// 420.685 us; speedup vs baseline: 1.5707x; 1.5707x over previous
//
#include <hip/hip_runtime.h>
#include <math.h>

// ---------------------------------------------------------------------------
// FFT_MLP_KAN v4: FFT features (27 cols/channel, duplicate phase folded) ->
// 4 KAN layers (dense GEMM, vectorized LDS, 256-thr blocks, deep split-K) ->
// 3 folded MLP heads. All fp32.
// ---------------------------------------------------------------------------

__device__ __forceinline__ float silu_f(float x) {
    return x / (1.f + __expf(-x));
}

// ---------------------------------------------------------------------------
// FFT features. Output 27 per (b,ch): [abs_prev(9), angle_cur(9), abs_cur(9)].
// (Reference's 4th block angle_cur duplicates block 2 -> folded into weights.)
// ---------------------------------------------------------------------------
__global__ __launch_bounds__(128) void fft_kernel(const float* __restrict__ x,
                                                  float* __restrict__ F0, int P) {
    __shared__ float xs[128 * 65];
    __shared__ float twc[288], tws[288];    // cos / sin(-2*pi*k*n/32)
    int tid = threadIdx.x;
    for (int t = tid; t < 288; t += 128) {
        int k = t >> 5, n = t & 31;
        int m = (k * n) & 31;
        float ang = -0.19634954084936207f * (float)m;
        float s, c;
        sincosf(ang, &s, &c);
        twc[t] = c; tws[t] = s;
    }
    int p0 = blockIdx.x * 128;
    for (int idx = tid; idx < 128 * 64; idx += 128) {
        int g = p0 * 64 + idx;
        float v = (g < P * 64) ? x[g] : 0.f;
        xs[(idx >> 6) * 65 + (idx & 63)] = v;
    }
    __syncthreads();
    int p = p0 + tid;
    if (p >= P) return;
    const float* row = &xs[tid * 65];
    float r[64];
#pragma unroll
    for (int n = 0; n < 64; ++n) r[n] = row[n];
    float outv[27];
#pragma unroll
    for (int k = 0; k < 9; ++k) {
        float rp = 0.f, ip = 0.f, rc = 0.f, ic = 0.f;
#pragma unroll
        for (int n = 0; n < 32; ++n) {
            float c = twc[k * 32 + n], s = tws[k * 32 + n];
            rp = fmaf(r[n], c, rp);
            ip = fmaf(r[n], s, ip);
            rc = fmaf(r[n + 32], c, rc);
            ic = fmaf(r[n + 32], s, ic);
        }
        float ap = sqrtf(fmaf(rp, rp, ip * ip));
        float ac = sqrtf(fmaf(rc, rc, ic * ic));
        float gc = atan2f(ic, rc);
        outv[k] = ap; outv[9 + k] = gc; outv[18 + k] = ac;
    }
    float* dst = &F0[(size_t)p * 27];
#pragma unroll
    for (int q = 0; q < 27; ++q) dst[q] = outv[q];
}

// ---------------------------------------------------------------------------
// One fused prep kernel: Wf1 (merged 378-col layout), Wf2..Wf4, heads fold.
// Wf layout: [(i*14 + c)*OUT + o]; c=0 base, c>=1 spline*scaler.
// ---------------------------------------------------------------------------
__device__ __forceinline__ float kval(const float* __restrict__ bw,
                                      const float* __restrict__ sw,
                                      const float* __restrict__ sc,
                                      int IN, int o, int s, int c) {
    if (c == 0) return bw[o * IN + s];
    return sw[((size_t)o * IN + s) * 13 + (c - 1)] * sc[o * IN + s];
}

__global__ void prep_all_kernel(float* __restrict__ Wf1, float* __restrict__ Wf2,
                                float* __restrict__ Wf3, float* __restrict__ Wf4,
                                float* __restrict__ W21, float* __restrict__ b21,
                                const float* k1b, const float* k1s, const float* k1c,
                                const float* k2b, const float* k2s, const float* k2c,
                                const float* k3b, const float* k3s, const float* k3c,
                                const float* k4b, const float* k4s, const float* k4c,
                                const float* W1, const float* b1,
                                const float* W2, const float* b2) {
    const int T1 = 378 * 14 * 80, T2 = 80 * 14 * 160, T3 = 160 * 14 * 80, T4 = 80 * 14 * 40;
    int id = blockIdx.x * 256 + threadIdx.x;
    if (id < T1) {
        int o = id % 80, rem = id / 80, c = rem % 14, i = rem / 14;
        int ch = i / 27, q = i % 27;
        int s1 = ch * 36 + q;
        float v = kval(k1b, k1s, k1c, 504, o, s1, c);
        if (q >= 9 && q < 18) v += kval(k1b, k1s, k1c, 504, o, s1 + 18, c);
        Wf1[id] = v;
        return;
    }
    id -= T1;
    if (id < T2) {
        int o = id % 160, rem = id / 160, c = rem % 14, i = rem / 14;
        Wf2[id] = kval(k2b, k2s, k2c, 80, o, i, c);
        return;
    }
    id -= T2;
    if (id < T3) {
        int o = id % 80, rem = id / 80, c = rem % 14, i = rem / 14;
        Wf3[id] = kval(k3b, k3s, k3c, 160, o, i, c);
        return;
    }
    id -= T3;
    if (id < T4) {
        int o = id % 40, rem = id / 40, c = rem % 14, i = rem / 14;
        Wf4[id] = kval(k4b, k4s, k4c, 80, o, i, c);
        return;
    }
    id -= T4;
    if (id < 3 * 20 * 40) {
        int k = id % 40, rem = id / 40, j = rem % 20, h = rem / 20;
        float a = 0.f;
        for (int m = 0; m < 40; ++m)
            a = fmaf(W2[(h * 20 + j) * 40 + m], W1[(h * 40 + m) * 40 + k], a);
        W21[id] = a;
    } else if (id < 3 * 20 * 40 + 60) {
        int t = id - 2400, j = t % 20, h = t / 20;
        float a = b2[h * 20 + j];
        for (int m = 0; m < 40; ++m)
            a = fmaf(W2[(h * 20 + j) * 40 + m], b1[h * 40 + m], a);
        b21[t] = a;
    }
}

// ---------------------------------------------------------------------------
// KAN layer v4: 256 threads (4 waves), BM rows, vectorized LDS, split-K over
// blockIdx.y, optional OUT-column half over blockIdx.z (tile width OUT_T of
// full row stride OUTF).
//  - Ws [kc28][ct][NRP=12]: 2x b128 + 1x b64 per (kc,thread). Banks: ct*12
//    mod 32 -> disjoint quads, broadcast within ct-group. Conflict-free.
//  - Ft [kc28][row BM]: b128 (MR=4) broadcast across ct-groups. Conflict-free.
//  - Features built by threads kk=tid/BM<2 (one row x one k each).
// ---------------------------------------------------------------------------
template <int OUT_T, int BM, int KC>
__global__ __launch_bounds__(256, 4) void kan4_kernel(const float* __restrict__ X, int IN,
                                                      int OUTF,
                                                      const float* __restrict__ Wf,
                                                      float* __restrict__ Yp, int B) {
    constexpr int NR = 10;
    constexpr int COLS_T = OUT_T / NR;       // 8 or 4
    constexpr int ROWS_T = 256 / COLS_T;     // 32 or 64
    constexpr int MR = BM / ROWS_T;          // 4 (BM=128) or 1 (BM=64)
    constexpr int NRP = 12;
    static_assert(COLS_T * NR == OUT_T, "cols");
    static_assert(ROWS_T * MR == BM, "rows");
    static_assert(KC % 2 == 0, "even KC");

    __shared__ float Ws[2 * 14 * COLS_T * NRP];
    __shared__ float Ft[2 * 14 * BM];

    const int tid = threadIdx.x;
    const int ct = tid % COLS_T, rt = tid / COLS_T;
    const int b0 = blockIdx.x * BM;
    const int ibase = blockIdx.y * KC;
    const int co = blockIdx.z * OUT_T;
    const int kk = tid / BM;
    const int rr = tid % BM;
    const bool fact = (kk < 2);

    float acc[MR][NR];
#pragma unroll
    for (int m = 0; m < MR; ++m)
#pragma unroll
        for (int n = 0; n < NR; ++n) acc[m][n] = 0.f;

    float xreg = 0.f;
    if (fact) xreg = X[(size_t)(b0 + rr) * IN + ibase + kk];

    for (int i0 = 0; i0 < KC; i0 += 2) {
        // ---- feature build: one (k,row) cell per thread ----
        if (fact) {
            float xs = xreg;
            float* dst = &Ft[kk * 14 * BM + rr];
            dst[0] = silu_f(xs);
#pragma unroll
            for (int c = 1; c < 14; ++c) dst[c * BM] = 0.f;
            float t10 = (xs + 0.3f) * 10.f;
            if (t10 >= 0.f && t10 < 16.f) {
                int j = (int)t10;
                float u = t10 - (float)j;
                float u2 = u * u, u3 = u2 * u, v = 1.f - u;
                float B0 = v * v * v * (1.f / 6.f);
                float B1 = (3.f * u3 - 6.f * u2 + 4.f) * (1.f / 6.f);
                float B2 = (-3.f * u3 + 3.f * u2 + 3.f * u + 1.f) * (1.f / 6.f);
                float B3 = u3 * (1.f / 6.f);
                int bs = j - 3;
#pragma unroll
                for (int t = 0; t < 4; ++t) {
                    int rw = bs + t;
                    float bb = (t == 0) ? B0 : (t == 1) ? B1 : (t == 2) ? B2 : B3;
                    if (rw >= 0 && rw <= 12) dst[(1 + rw) * BM] = bb;
                }
            }
        }
        // ---- stage weights (coalesced global read, swizzled LDS write) ----
        {
            const float* wsrc = Wf + (size_t)(ibase + i0) * 14 * OUTF + co;
            for (int t = tid; t < 2 * 14 * OUT_T; t += 256) {
                int o = t % OUT_T;
                int kc = t / OUT_T;          // 0..27 = k*14+c
                Ws[(kc * COLS_T + o / NR) * NRP + (o % NR)] = wsrc[(size_t)kc * OUTF + o];
            }
        }
        // ---- prefetch next chunk's x ----
        float xn = 0.f;
        if (fact && (i0 + 2) < KC)
            xn = X[(size_t)(b0 + rr) * IN + ibase + i0 + 2 + kk];
        __syncthreads();
        // ---- FMA: 28 (k,c) planes, all-vector LDS reads ----
#pragma unroll
        for (int kc = 0; kc < 28; ++kc) {
            const float* wb = &Ws[(kc * COLS_T + ct) * NRP];
            float4 w0 = *(const float4*)(wb);
            float4 w1 = *(const float4*)(wb + 4);
            float2 w2 = *(const float2*)(wb + 8);
            float wn[NR] = {w0.x, w0.y, w0.z, w0.w, w1.x, w1.y, w1.z, w1.w, w2.x, w2.y};
            const float* fb = &Ft[kc * BM + rt * MR];
            float xm[MR];
            if constexpr (MR == 4) {
                float4 f = *(const float4*)fb;
                xm[0] = f.x; xm[1] = f.y; xm[2] = f.z; xm[3] = f.w;
            } else if constexpr (MR == 2) {
                float2 f = *(const float2*)fb;
                xm[0] = f.x; xm[1] = f.y;
            } else {
                xm[0] = fb[0];
            }
#pragma unroll
            for (int m = 0; m < MR; ++m)
#pragma unroll
                for (int n = 0; n < NR; ++n) acc[m][n] = fmaf(xm[m], wn[n], acc[m][n]);
        }
        __syncthreads();
        xreg = xn;
    }

    // ---- store partial ----
    float* ydst = Yp + (size_t)blockIdx.y * B * OUTF;
#pragma unroll
    for (int m = 0; m < MR; ++m) {
        float* yr = ydst + (size_t)(b0 + rt * MR + m) * OUTF + co + ct * NR;
#pragma unroll
        for (int nn = 0; nn < NR / 2; ++nn)
            *(float2*)(yr + 2 * nn) = make_float2(acc[m][2 * nn], acc[m][2 * nn + 1]);
    }
}

__global__ void reduce_kernel(float* __restrict__ Y, const float* __restrict__ Yp,
                              int N, int KS) {
    int t = blockIdx.x * 256 + threadIdx.x;
    if (t >= N) return;
    float a = 0.f;
    for (int s = 0; s < KS; ++s) a += Yp[(size_t)s * N + t];
    Y[t] = a;
}

// ---------------------------------------------------------------------------
// Heads: one thread per (b, head).
// ---------------------------------------------------------------------------
__global__ __launch_bounds__(256) void heads_kernel(const float* __restrict__ h4,
                                                    const float* __restrict__ W21,
                                                    const float* __restrict__ b21,
                                                    const float* __restrict__ W3,
                                                    const float* __restrict__ b3,
                                                    float* __restrict__ out, int B) {
    __shared__ float w21s[2400], b21s[60], w3s[60], b3s[3];
    int tid = threadIdx.x;
    for (int t = tid; t < 2400; t += 256) w21s[t] = W21[t];
    if (tid < 60) { b21s[tid] = b21[tid]; w3s[tid] = W3[tid]; }
    if (tid < 3) b3s[tid] = b3[tid];
    __syncthreads();
    int id = blockIdx.x * 256 + tid;
    if (id >= B * 3) return;
    int b = id / 3, h = id % 3;
    const float* hr = &h4[(size_t)b * 40];
    float hv[40];
#pragma unroll
    for (int m = 0; m < 40; ++m) hv[m] = hr[m];
    float z = b3s[h];
#pragma unroll
    for (int j = 0; j < 20; ++j) {
        float y = b21s[h * 20 + j];
        const float* wr = &w21s[(h * 20 + j) * 40];
#pragma unroll
        for (int m = 0; m < 40; ++m) y = fmaf(wr[m], hv[m], y);
        y = (y >= 0.f) ? y : 0.05f * y;
        z = fmaf(w3s[h * 20 + j], y, z);
    }
    out[id] = 1.f / (1.f + __expf(-z));
}

// ---------------------------------------------------------------------------
extern "C" void kernel_launch(void* const* d_in, const int* in_sizes, int n_in,
                              void* d_out, int out_size, void* d_ws, size_t ws_size,
                              hipStream_t stream) {
    const float* x   = (const float*)d_in[0];
    const float* k1b = (const float*)d_in[1];
    const float* k1s = (const float*)d_in[2];
    const float* k1c = (const float*)d_in[3];
    const float* k2b = (const float*)d_in[4];
    const float* k2s = (const float*)d_in[5];
    const float* k2c = (const float*)d_in[6];
    const float* k3b = (const float*)d_in[7];
    const float* k3s = (const float*)d_in[8];
    const float* k3c = (const float*)d_in[9];
    const float* k4b = (const float*)d_in[10];
    const float* k4s = (const float*)d_in[11];
    const float* k4c = (const float*)d_in[12];
    const float* hW1 = (const float*)d_in[13];
    const float* hb1 = (const float*)d_in[14];
    const float* hW2 = (const float*)d_in[15];
    const float* hb2 = (const float*)d_in[16];
    const float* hW3 = (const float*)d_in[17];
    const float* hb3 = (const float*)d_in[18];
    float* out = (float*)d_out;

    int B = in_sizes[0] / (64 * 14);
    int P = B * 14;

    float* ws = (float*)d_ws;
    size_t off = 0;
    float* Wf1 = ws + off; off += 378 * 14 * 80;
    float* Wf2 = ws + off; off += 80 * 14 * 160;
    float* Wf3 = ws + off; off += 160 * 14 * 80;
    float* Wf4 = ws + off; off += 80 * 14 * 40;
    float* W21 = ws + off; off += 2400;
    float* b21 = ws + off; off += 60;
    float* F0  = ws + off; off += (size_t)B * 378;
    float* h1  = ws + off; off += (size_t)B * 80;
    float* h2  = ws + off; off += (size_t)B * 160;
    float* h3  = ws + off; off += (size_t)B * 80;
    float* h4  = ws + off; off += (size_t)B * 40;
    float* Yp  = ws + off;                       // remainder: split-K partials
    size_t cap = (ws_size / 4 > off) ? (ws_size / 4 - off) : 0;

    // runtime split-K depth selection (ws_size constant -> same path each call)
    int S1 = (cap >= (size_t)21 * B * 80)  ? 21 : 9;   // L1: KC 18 / 42
    int S2 = (cap >= (size_t)8  * B * 160) ? 8  : 4;   // L2: KC 10 / 20
    int S3 = (cap >= (size_t)16 * B * 80)  ? 16 : 8;   // L3: KC 10 / 20
    const int S4 = 8;                                  // L4: KC 10

    // ---- prep (1 dispatch) ----
    {
        int total = 378 * 14 * 80 + 80 * 14 * 160 + 160 * 14 * 80 + 80 * 14 * 40 + 2460;
        prep_all_kernel<<<(total + 255) / 256, 256, 0, stream>>>(
            Wf1, Wf2, Wf3, Wf4, W21, b21,
            k1b, k1s, k1c, k2b, k2s, k2c, k3b, k3s, k3c, k4b, k4s, k4c,
            hW1, hb1, hW2, hb2);
    }

    // ---- FFT features ----
    fft_kernel<<<(P + 127) / 128, 128, 0, stream>>>(x, F0, P);

    // ---- L1: 378 -> 80 ----
    if (S1 == 21) kan4_kernel<80, 128, 18><<<dim3(B / 128, 21, 1), 256, 0, stream>>>(F0, 378, 80, Wf1, Yp, B);
    else          kan4_kernel<80, 128, 42><<<dim3(B / 128, 9, 1), 256, 0, stream>>>(F0, 378, 80, Wf1, Yp, B);
    reduce_kernel<<<((B * 80) + 255) / 256, 256, 0, stream>>>(h1, Yp, B * 80, S1);

    // ---- L2: 80 -> 160 (column halves via blockIdx.z) ----
    if (S2 == 8) kan4_kernel<80, 128, 10><<<dim3(B / 128, 8, 2), 256, 0, stream>>>(h1, 80, 160, Wf2, Yp, B);
    else         kan4_kernel<80, 128, 20><<<dim3(B / 128, 4, 2), 256, 0, stream>>>(h1, 80, 160, Wf2, Yp, B);
    reduce_kernel<<<((B * 160) + 255) / 256, 256, 0, stream>>>(h2, Yp, B * 160, S2);

    // ---- L3: 160 -> 80 ----
    if (S3 == 16) kan4_kernel<80, 128, 10><<<dim3(B / 128, 16, 1), 256, 0, stream>>>(h2, 160, 80, Wf3, Yp, B);
    else          kan4_kernel<80, 128, 20><<<dim3(B / 128, 8, 1), 256, 0, stream>>>(h2, 160, 80, Wf3, Yp, B);
    reduce_kernel<<<((B * 80) + 255) / 256, 256, 0, stream>>>(h3, Yp, B * 80, S3);

    // ---- L4: 80 -> 40 (BM=64 for grid depth) ----
    kan4_kernel<40, 64, 10><<<dim3(B / 64, S4, 1), 256, 0, stream>>>(h3, 80, 40, Wf4, Yp, B);
    reduce_kernel<<<((B * 40) + 255) / 256, 256, 0, stream>>>(h4, Yp, B * 40, S4);

    // ---- heads ----
    heads_kernel<<<(B * 3 + 255) / 256, 256, 0, stream>>>(h4, W21, b21, hW3, hb3, out, B);

    (void)n_in; (void)out_size;
}

// Round 7
// 389.153 us; speedup vs baseline: 1.6979x; 1.0810x over previous
//
#include <hip/hip_runtime.h>
#include <math.h>

// ---------------------------------------------------------------------------
// FFT_MLP_KAN v5: FFT -> transpose -> 4 KAN layers (transposed activations,
// chunk-padded weights, reg-staged LDS pipeline) -> 3 folded heads. All fp32.
// ---------------------------------------------------------------------------

__device__ __forceinline__ float silu_f(float x) {
    return x / (1.f + __expf(-x));
}

// ---------------------------------------------------------------------------
// FFT features -> F0 [P][27] row-major (27 = abs_prev9, angle_cur9, abs_cur9;
// reference's 4th block duplicates block 2 -> folded into L1 weights).
// ---------------------------------------------------------------------------
__global__ __launch_bounds__(128) void fft_kernel(const float* __restrict__ x,
                                                  float* __restrict__ F0, int P) {
    __shared__ float xs[128 * 65];
    __shared__ float twc[288], tws[288];    // cos / sin(-2*pi*k*n/32)
    int tid = threadIdx.x;
    for (int t = tid; t < 288; t += 128) {
        int k = t >> 5, n = t & 31;
        int m = (k * n) & 31;
        float ang = -0.19634954084936207f * (float)m;
        float s, c;
        sincosf(ang, &s, &c);
        twc[t] = c; tws[t] = s;
    }
    int p0 = blockIdx.x * 128;
    for (int idx = tid; idx < 128 * 64; idx += 128) {
        int g = p0 * 64 + idx;
        float v = (g < P * 64) ? x[g] : 0.f;
        xs[(idx >> 6) * 65 + (idx & 63)] = v;
    }
    __syncthreads();
    int p = p0 + tid;
    if (p >= P) return;
    const float* row = &xs[tid * 65];
    float r[64];
#pragma unroll
    for (int n = 0; n < 64; ++n) r[n] = row[n];
    float outv[27];
#pragma unroll
    for (int k = 0; k < 9; ++k) {
        float rp = 0.f, ip = 0.f, rc = 0.f, ic = 0.f;
#pragma unroll
        for (int n = 0; n < 32; ++n) {
            float c = twc[k * 32 + n], s = tws[k * 32 + n];
            rp = fmaf(r[n], c, rp);
            ip = fmaf(r[n], s, ip);
            rc = fmaf(r[n + 32], c, rc);
            ic = fmaf(r[n + 32], s, ic);
        }
        float ap = sqrtf(fmaf(rp, rp, ip * ip));
        float ac = sqrtf(fmaf(rc, rc, ic * ic));
        float gc = atan2f(ic, rc);
        outv[k] = ap; outv[9 + k] = gc; outv[18 + k] = ac;
    }
    float* dst = &F0[(size_t)p * 27];
#pragma unroll
    for (int q = 0; q < 27; ++q) dst[q] = outv[q];
}

// ---------------------------------------------------------------------------
// Transpose F0 [B*14][27] -> F0T [378][B]. Tile: 32 b-values per block.
// ---------------------------------------------------------------------------
__global__ __launch_bounds__(256) void transpose_f0_kernel(const float* __restrict__ F0,
                                                           float* __restrict__ F0T, int B) {
    __shared__ float t[448 * 27];            // 32 b x 14 ch x 27 q (48.4 KB)
    int b0 = blockIdx.x * 32;
    const float* src = F0 + (size_t)b0 * 14 * 27;
    for (int idx = threadIdx.x; idx < 448 * 27; idx += 256) t[idx] = src[idx];
    __syncthreads();
    for (int idx = threadIdx.x; idx < 378 * 32; idx += 256) {
        int i = idx >> 5, bb = idx & 31;     // i = ch*27+q
        int ch = i / 27, q = i - ch * 27;
        F0T[(size_t)i * B + b0 + bb] = t[(bb * 14 + ch) * 27 + q];
    }
}

// ---------------------------------------------------------------------------
// Prep: chunk-padded fused weights. Layout per layer:
//   Wfp[((jg*NHALF + half) * 28*CT*12) + (kc*CT + ct)*12 + r]
// where jg = i/2 (chunk of 2 inputs), kc = (i&1)*14 + c, o = half*OUT_T+ct*10+r.
// c=0 -> base_w, c>=1 -> spline_w*scaler. r in [10,12) pads to 0.
// ---------------------------------------------------------------------------
__device__ __forceinline__ float kval(const float* __restrict__ bw,
                                      const float* __restrict__ sw,
                                      const float* __restrict__ sc,
                                      int IN, int o, int s, int c) {
    if (c == 0) return bw[o * IN + s];
    return sw[((size_t)o * IN + s) * 13 + (c - 1)] * sc[o * IN + s];
}

__global__ void prep_all_kernel(float* __restrict__ Wfp1, float* __restrict__ Wfp2,
                                float* __restrict__ Wfp3, float* __restrict__ Wfp4,
                                float* __restrict__ W21, float* __restrict__ b21,
                                const float* k1b, const float* k1s, const float* k1c,
                                const float* k2b, const float* k2s, const float* k2c,
                                const float* k3b, const float* k3s, const float* k3c,
                                const float* k4b, const float* k4s, const float* k4c,
                                const float* W1, const float* b1,
                                const float* W2, const float* b2) {
    const int T1 = 189 * 2688, T2 = 40 * 2 * 2688, T3 = 80 * 2688, T4 = 40 * 1344;
    int id = blockIdx.x * 256 + threadIdx.x;
    if (id < T1) {                            // L1: 378 in (27-fold), 80 out
        int jg = id / 2688, t = id % 2688;
        int kc = t / 96, t2 = t % 96, ct = t2 / 12, r = t2 % 12;
        int i = 2 * jg + kc / 14, c = kc % 14, o = ct * 10 + r;
        float v = 0.f;
        if (r < 10) {
            int ch = i / 27, q = i - ch * 27, s1 = ch * 36 + q;
            v = kval(k1b, k1s, k1c, 504, o, s1, c);
            if (q >= 9 && q < 18) v += kval(k1b, k1s, k1c, 504, o, s1 + 18, c);
        }
        Wfp1[id] = v; return;
    }
    id -= T1;
    if (id < T2) {                            // L2: 80 in, 160 out (2 halves)
        int jg = id / (2 * 2688), rem = id % (2 * 2688), half = rem / 2688, t = rem % 2688;
        int kc = t / 96, t2 = t % 96, ct = t2 / 12, r = t2 % 12;
        int i = 2 * jg + kc / 14, c = kc % 14, o = half * 80 + ct * 10 + r;
        Wfp2[id] = (r < 10) ? kval(k2b, k2s, k2c, 80, o, i, c) : 0.f; return;
    }
    id -= T2;
    if (id < T3) {                            // L3: 160 in, 80 out
        int jg = id / 2688, t = id % 2688;
        int kc = t / 96, t2 = t % 96, ct = t2 / 12, r = t2 % 12;
        int i = 2 * jg + kc / 14, c = kc % 14, o = ct * 10 + r;
        Wfp3[id] = (r < 10) ? kval(k3b, k3s, k3c, 160, o, i, c) : 0.f; return;
    }
    id -= T3;
    if (id < T4) {                            // L4: 80 in, 40 out
        int jg = id / 1344, t = id % 1344;
        int kc = t / 48, t2 = t % 48, ct = t2 / 12, r = t2 % 12;
        int i = 2 * jg + kc / 14, c = kc % 14, o = ct * 10 + r;
        Wfp4[id] = (r < 10) ? kval(k4b, k4s, k4c, 80, o, i, c) : 0.f; return;
    }
    id -= T4;
    if (id < 3 * 20 * 40) {                   // heads fold: W21 = W2 @ W1
        int k = id % 40, rem = id / 40, j = rem % 20, h = rem / 20;
        float a = 0.f;
        for (int m = 0; m < 40; ++m)
            a = fmaf(W2[(h * 20 + j) * 40 + m], W1[(h * 40 + m) * 40 + k], a);
        W21[id] = a;
    } else if (id < 3 * 20 * 40 + 60) {
        int t = id - 2400, j = t % 20, h = t / 20;
        float a = b2[h * 20 + j];
        for (int m = 0; m < 40; ++m)
            a = fmaf(W2[(h * 20 + j) * 40 + m], b1[h * 40 + m], a);
        b21[t] = a;
    }
}

// ---------------------------------------------------------------------------
// KAN layer v5: transposed activations XT [IN][B] -> partials YpT [s][OUTF][B].
// 256 threads, BM=128 rows, chunk of 2 inputs per iteration.
// Pipeline per chunk: barrier; commit staged weights reg->LDS + build features;
// issue next chunk's global loads; barrier; FMA (vector LDS reads).
// Thread map: rt = tid % ROWS_T (fast -> coalesced b), ct = tid / ROWS_T.
// ---------------------------------------------------------------------------
template <int OUT_T, int KC, int NHALF>
__global__ __launch_bounds__(256) void kan5_kernel(const float* __restrict__ XT, int B,
                                                   const float* __restrict__ Wfp,
                                                   float* __restrict__ YpT, int OUTF) {
    constexpr int BM = 128;
    constexpr int NR = 10;
    constexpr int COLS_T = OUT_T / NR;       // 8 or 4
    constexpr int ROWS_T = 256 / COLS_T;     // 32 or 64
    constexpr int MR = BM / ROWS_T;          // 4 or 2
    constexpr int NW = 28 * COLS_T * 12;     // staged floats per chunk
    constexpr int NCH = KC / 2;
    constexpr int WSTG = (NW + 255) / 256;
    static_assert(COLS_T * NR == OUT_T, "cols");
    static_assert(ROWS_T * MR == BM, "rows");
    static_assert(KC % 2 == 0, "even KC");

    __shared__ float Ws[NW];
    __shared__ float Ft[28 * BM];

    const int tid = threadIdx.x;
    const int rt = tid % ROWS_T, ct = tid / ROWS_T;
    const int b0 = blockIdx.x * BM;
    const int s = blockIdx.y;
    const int half = blockIdx.z;
    const int ibase = s * KC;
    const int kk = tid >> 7;                 // feature cell: k in {0,1}
    const int rr = tid & 127;                // feature cell: row

    float acc[MR][NR];
#pragma unroll
    for (int m = 0; m < MR; ++m)
#pragma unroll
        for (int n = 0; n < NR; ++n) acc[m][n] = 0.f;

    const size_t wbase0 = ((size_t)(ibase / 2) * NHALF + half) * NW;
    float wreg[WSTG];
#pragma unroll
    for (int u = 0; u < WSTG; ++u) {
        int t = tid + u * 256;
        wreg[u] = (t < NW) ? Wfp[wbase0 + t] : 0.f;
    }
    float xreg = XT[(size_t)(ibase + kk) * B + b0 + rr];

    for (int j = 0; j < NCH; ++j) {
        __syncthreads();                     // previous chunk's readers done
        // ---- commit staged weights (linear, conflict-free) ----
#pragma unroll
        for (int u = 0; u < WSTG; ++u) {
            int t = tid + u * 256;
            if (t < NW) Ws[t] = wreg[u];
        }
        // ---- build features for this chunk ----
        {
            float xs = xreg;
            float* dst = &Ft[kk * 14 * BM + rr];
            dst[0] = silu_f(xs);
#pragma unroll
            for (int c = 1; c < 14; ++c) dst[c * BM] = 0.f;
            float t10 = (xs + 0.3f) * 10.f;
            if (t10 >= 0.f && t10 < 16.f) {
                int jj = (int)t10;
                float u = t10 - (float)jj;
                float u2 = u * u, u3 = u2 * u, v = 1.f - u;
                float B0 = v * v * v * (1.f / 6.f);
                float B1 = (3.f * u3 - 6.f * u2 + 4.f) * (1.f / 6.f);
                float B2 = (-3.f * u3 + 3.f * u2 + 3.f * u + 1.f) * (1.f / 6.f);
                float B3 = u3 * (1.f / 6.f);
                int bs = jj - 3;
#pragma unroll
                for (int t = 0; t < 4; ++t) {
                    int rw = bs + t;
                    float bb = (t == 0) ? B0 : (t == 1) ? B1 : (t == 2) ? B2 : B3;
                    if (rw >= 0 && rw <= 12) dst[(1 + rw) * BM] = bb;
                }
            }
        }
        // ---- issue next chunk's global loads (hide under FMA below) ----
        if (j + 1 < NCH) {
            const size_t wb = wbase0 + (size_t)(j + 1) * NHALF * NW;
#pragma unroll
            for (int u = 0; u < WSTG; ++u) {
                int t = tid + u * 256;
                if (t < NW) wreg[u] = Wfp[wb + t];
            }
            xreg = XT[(size_t)(ibase + 2 * (j + 1) + kk) * B + b0 + rr];
        }
        __syncthreads();                     // Ws/Ft visible
        // ---- FMA: 28 (k,c) planes ----
#pragma unroll
        for (int kc = 0; kc < 28; ++kc) {
            const float* wb = &Ws[(kc * COLS_T + ct) * 12];
            float4 w0 = *(const float4*)(wb);
            float4 w1 = *(const float4*)(wb + 4);
            float2 w2 = *(const float2*)(wb + 8);
            float wn[NR] = {w0.x, w0.y, w0.z, w0.w, w1.x, w1.y, w1.z, w1.w, w2.x, w2.y};
            const float* fb = &Ft[kc * BM + rt * MR];
            float xm[MR];
            if constexpr (MR == 4) {
                float4 f = *(const float4*)fb;
                xm[0] = f.x; xm[1] = f.y; xm[2] = f.z; xm[3] = f.w;
            } else {
                float2 f = *(const float2*)fb;
                xm[0] = f.x; xm[1] = f.y;
            }
#pragma unroll
            for (int m = 0; m < MR; ++m)
#pragma unroll
                for (int n = 0; n < NR; ++n) acc[m][n] = fmaf(xm[m], wn[n], acc[m][n]);
        }
    }

    // ---- store partial: float4/float2 along b (coalesced) ----
    float* yd = YpT + (size_t)s * OUTF * B + (size_t)(half * OUT_T) * B;
#pragma unroll
    for (int n = 0; n < NR; ++n) {
        float* p = yd + (size_t)(ct * NR + n) * B + b0 + rt * MR;
        if constexpr (MR == 4)
            *(float4*)p = make_float4(acc[0][n], acc[1][n], acc[2][n], acc[3][n]);
        else
            *(float2*)p = make_float2(acc[0][n], acc[1][n]);
    }
}

__global__ void reduce_kernel(float* __restrict__ Y, const float* __restrict__ Yp,
                              int N, int KS) {
    int t = blockIdx.x * 256 + threadIdx.x;
    if (t >= N) return;
    float a = 0.f;
    for (int s = 0; s < KS; ++s) a += Yp[(size_t)s * N + t];
    Y[t] = a;
}

// ---------------------------------------------------------------------------
// Heads: one thread per (b, head); h4T is [40][B].
// ---------------------------------------------------------------------------
__global__ __launch_bounds__(256) void heads_kernel(const float* __restrict__ h4T,
                                                    const float* __restrict__ W21,
                                                    const float* __restrict__ b21,
                                                    const float* __restrict__ W3,
                                                    const float* __restrict__ b3,
                                                    float* __restrict__ out, int B) {
    __shared__ float w21s[2400], b21s[60], w3s[60], b3s[3];
    int tid = threadIdx.x;
    for (int t = tid; t < 2400; t += 256) w21s[t] = W21[t];
    if (tid < 60) { b21s[tid] = b21[tid]; w3s[tid] = W3[tid]; }
    if (tid < 3) b3s[tid] = b3[tid];
    __syncthreads();
    int id = blockIdx.x * 256 + tid;
    if (id >= B * 3) return;
    int b = id / 3, h = id % 3;
    float hv[40];
#pragma unroll
    for (int m = 0; m < 40; ++m) hv[m] = h4T[(size_t)m * B + b];
    float z = b3s[h];
#pragma unroll
    for (int j = 0; j < 20; ++j) {
        float y = b21s[h * 20 + j];
        const float* wr = &w21s[(h * 20 + j) * 40];
#pragma unroll
        for (int m = 0; m < 40; ++m) y = fmaf(wr[m], hv[m], y);
        y = (y >= 0.f) ? y : 0.05f * y;
        z = fmaf(w3s[h * 20 + j], y, z);
    }
    out[id] = 1.f / (1.f + __expf(-z));
}

// ---------------------------------------------------------------------------
extern "C" void kernel_launch(void* const* d_in, const int* in_sizes, int n_in,
                              void* d_out, int out_size, void* d_ws, size_t ws_size,
                              hipStream_t stream) {
    const float* x   = (const float*)d_in[0];
    const float* k1b = (const float*)d_in[1];
    const float* k1s = (const float*)d_in[2];
    const float* k1c = (const float*)d_in[3];
    const float* k2b = (const float*)d_in[4];
    const float* k2s = (const float*)d_in[5];
    const float* k2c = (const float*)d_in[6];
    const float* k3b = (const float*)d_in[7];
    const float* k3s = (const float*)d_in[8];
    const float* k3c = (const float*)d_in[9];
    const float* k4b = (const float*)d_in[10];
    const float* k4s = (const float*)d_in[11];
    const float* k4c = (const float*)d_in[12];
    const float* hW1 = (const float*)d_in[13];
    const float* hb1 = (const float*)d_in[14];
    const float* hW2 = (const float*)d_in[15];
    const float* hb2 = (const float*)d_in[16];
    const float* hW3 = (const float*)d_in[17];
    const float* hb3 = (const float*)d_in[18];
    float* out = (float*)d_out;

    int B = in_sizes[0] / (64 * 14);
    int P = B * 14;

    float* ws = (float*)d_ws;
    size_t off = 0;
    float* Wfp1 = ws + off; off += 189 * 2688;
    float* Wfp2 = ws + off; off += 40 * 2 * 2688;
    float* Wfp3 = ws + off; off += 80 * 2688;
    float* Wfp4 = ws + off; off += 40 * 1344;
    float* W21  = ws + off; off += 2400;
    float* b21  = ws + off; off += 60;
    float* F0T  = ws + off; off += (size_t)B * 378;
    float* h1T  = ws + off; off += (size_t)B * 80;
    float* h2T  = ws + off; off += (size_t)B * 160;
    float* h3T  = ws + off; off += (size_t)B * 80;
    float* h4T  = ws + off; off += (size_t)B * 40;
    // shared region: F0 (row-major, dead after transpose) aliases Yp
    float* F0   = ws + off;
    float* Yp   = ws + off;
    size_t cap = (ws_size / 4 > off) ? (ws_size / 4 - off) : 0;
    // F0 needs B*378 of the shared region during fft+transpose only.
    // split-K depth selection (ws_size constant -> same path every call)
    int S1 = (cap >= (size_t)21 * B * 80) ? 21 : (cap >= (size_t)9 * B * 80) ? 9
           : (cap >= (size_t)7 * B * 80) ? 7 : 3;
    int S2 = (cap >= (size_t)10 * B * 160) ? 10 : (cap >= (size_t)5 * B * 160) ? 5 : 2;
    int S3 = (cap >= (size_t)20 * B * 80) ? 20 : (cap >= (size_t)8 * B * 80) ? 8 : 4;
    int S4 = (cap >= (size_t)10 * B * 40) ? 10 : 2;

    // ---- prep (1 dispatch) ----
    {
        int total = 189 * 2688 + 40 * 2 * 2688 + 80 * 2688 + 40 * 1344 + 2460;
        prep_all_kernel<<<(total + 255) / 256, 256, 0, stream>>>(
            Wfp1, Wfp2, Wfp3, Wfp4, W21, b21,
            k1b, k1s, k1c, k2b, k2s, k2c, k3b, k3s, k3c, k4b, k4s, k4c,
            hW1, hb1, hW2, hb2);
    }

    // ---- FFT -> transpose ----
    fft_kernel<<<(P + 127) / 128, 128, 0, stream>>>(x, F0, P);
    transpose_f0_kernel<<<B / 32, 256, 0, stream>>>(F0, F0T, B);

    // ---- L1: 378 -> 80 ----
    if (S1 == 21)     kan5_kernel<80, 18, 1><<<dim3(B / 128, 21, 1), 256, 0, stream>>>(F0T, B, Wfp1, Yp, 80);
    else if (S1 == 9) kan5_kernel<80, 42, 1><<<dim3(B / 128, 9, 1), 256, 0, stream>>>(F0T, B, Wfp1, Yp, 80);
    else if (S1 == 7) kan5_kernel<80, 54, 1><<<dim3(B / 128, 7, 1), 256, 0, stream>>>(F0T, B, Wfp1, Yp, 80);
    else              kan5_kernel<80, 126, 1><<<dim3(B / 128, 3, 1), 256, 0, stream>>>(F0T, B, Wfp1, Yp, 80);
    reduce_kernel<<<((B * 80) + 255) / 256, 256, 0, stream>>>(h1T, Yp, B * 80, S1);

    // ---- L2: 80 -> 160 (2 column halves) ----
    if (S2 == 10)     kan5_kernel<80, 8, 2><<<dim3(B / 128, 10, 2), 256, 0, stream>>>(h1T, B, Wfp2, Yp, 160);
    else if (S2 == 5) kan5_kernel<80, 16, 2><<<dim3(B / 128, 5, 2), 256, 0, stream>>>(h1T, B, Wfp2, Yp, 160);
    else              kan5_kernel<80, 40, 2><<<dim3(B / 128, 2, 2), 256, 0, stream>>>(h1T, B, Wfp2, Yp, 160);
    reduce_kernel<<<((B * 160) + 255) / 256, 256, 0, stream>>>(h2T, Yp, B * 160, S2);

    // ---- L3: 160 -> 80 ----
    if (S3 == 20)     kan5_kernel<80, 8, 1><<<dim3(B / 128, 20, 1), 256, 0, stream>>>(h2T, B, Wfp3, Yp, 80);
    else if (S3 == 8) kan5_kernel<80, 20, 1><<<dim3(B / 128, 8, 1), 256, 0, stream>>>(h2T, B, Wfp3, Yp, 80);
    else              kan5_kernel<80, 40, 1><<<dim3(B / 128, 4, 1), 256, 0, stream>>>(h2T, B, Wfp3, Yp, 80);
    reduce_kernel<<<((B * 80) + 255) / 256, 256, 0, stream>>>(h3T, Yp, B * 80, S3);

    // ---- L4: 80 -> 40 ----
    if (S4 == 10) kan5_kernel<40, 8, 1><<<dim3(B / 128, 10, 1), 256, 0, stream>>>(h3T, B, Wfp4, Yp, 40);
    else          kan5_kernel<40, 40, 1><<<dim3(B / 128, 2, 1), 256, 0, stream>>>(h3T, B, Wfp4, Yp, 40);
    reduce_kernel<<<((B * 40) + 255) / 256, 256, 0, stream>>>(h4T, Yp, B * 40, S4);

    // ---- heads ----
    heads_kernel<<<(B * 3 + 255) / 256, 256, 0, stream>>>(h4T, W21, b21, hW3, hb3, out, B);

    (void)n_in; (void)out_size;
}